// Round 3
// baseline (101.123 us; speedup 1.0000x reference)
//
#include <hip/hip_runtime.h>
#include <hip/hip_bf16.h>
#include <stdint.h>

// ---------------------------------------------------------------------------
// MF cosine-similarity, test path:
//   C[u][i] = Un[u].Vn[i]; Un/Vn = fp32-normalized rows rounded to bf16.
// GEMM: 128x128 tile, 8 waves (32x64 each, 512 thr), BK=64, 2-phase
// double-buffered prefetch, XOR-swizzled LDS (pre-swizzled global source,
// 2-way-free reads), swapped-operand MFMA -> f32x4 stores, bijective XCD
// swizzle (4096 blocks = 512/XCD). Occupancy: 2 blk/CU x 8 waves = 16
// waves/CU (2x R2) to overlap the end-of-block C-store drains.
// ---------------------------------------------------------------------------

#define LDIM 256
#define NROWS 8192
#define NDIM 8192
#define BM 128
#define BN 128
#define BK 64

typedef __bf16 bf16x8 __attribute__((ext_vector_type(8)));
typedef float f32x4 __attribute__((ext_vector_type(4)));

__device__ __forceinline__ unsigned short f2bf_rne(float f) {
  union { float f; uint32_t u; } c;
  c.f = f;
  uint32_t u = c.u;
  u += 0x7FFFu + ((u >> 16) & 1u);   // round-to-nearest-even
  return (unsigned short)(u >> 16);
}

// One wave per row, both tables in one launch: 256 f32 -> norm -> 256 bf16.
__global__ __launch_bounds__(256) void normalize_both(
    const float* __restrict__ userw, const float* __restrict__ itemw,
    unsigned short* __restrict__ dst) {
  const int wave = threadIdx.x >> 6;
  const int lane = threadIdx.x & 63;
  const int row = blockIdx.x * 4 + wave;               // 0..16383
  const float* src = (row < NROWS)
                         ? userw + (size_t)row * LDIM
                         : itemw + (size_t)(row - NROWS) * LDIM;

  const float4 v = reinterpret_cast<const float4*>(src)[lane];
  float ss = v.x * v.x + v.y * v.y + v.z * v.z + v.w * v.w;
#pragma unroll
  for (int off = 32; off; off >>= 1) ss += __shfl_xor(ss, off, 64);
  const float rn = 1.0f / fmaxf(sqrtf(ss), 1e-8f);

  ushort4 o;
  o.x = f2bf_rne(v.x * rn);
  o.y = f2bf_rne(v.y * rn);
  o.z = f2bf_rne(v.z * rn);
  o.w = f2bf_rne(v.w * rn);
  reinterpret_cast<ushort4*>(dst + (size_t)row * LDIM)[lane] = o;
}

__device__ __forceinline__ void gld_lds16(const __bf16* g, __bf16* l) {
  __builtin_amdgcn_global_load_lds(
      (const __attribute__((address_space(1))) uint32_t*)g,
      (__attribute__((address_space(3))) uint32_t*)l, 16, 0, 0);
}

// NT GEMM: C[8192][8192] f32 = A[8192][256] * B[8192][256]^T, bf16 inputs.
__global__ __launch_bounds__(512) void cos_gemm(
    const __bf16* __restrict__ A, const __bf16* __restrict__ B,
    float* __restrict__ C) {
  __shared__ __align__(16) __bf16 As[2][BM * BK];   // 16 KB per buf
  __shared__ __align__(16) __bf16 Bs[2][BN * BK];   // total 64 KB

  const int tid = threadIdx.x;
  const int wid = tid >> 6;                // 0..7
  const int lane = tid & 63;

  // Bijective XCD swizzle: 4096 blocks, 512 per XCD; within an XCD,
  // consecutive swz share the A-panel (bm) and sweep bn (B = 4 MB = L2).
  const int swz = (blockIdx.x & 7) * 512 + (blockIdx.x >> 3);
  const int bm = swz >> 6;
  const int bn = swz & 63;

  const int wr = wid >> 1;                 // 0..3 -> 32-row slab
  const int wc = wid & 1;                  // 0..1 -> 64-col slab

  // ---- staging map: linear LDS dest, PRE-SWIZZLED global source ---------
  // 128x64 bf16 tile = 1024 16B-chunks; chunk = c*512 + tid;
  // row = c*64 + (tid>>3); linear col-byte = (tid&7)<<4;
  // stored-at(cb) = cb ^ ((row&7)<<4), row&7 = (tid>>3)&7.
  const int srow = tid >> 3;                                   // + c*64/call
  const int scb = (((tid & 7) ^ (srow & 7)) << 4);             // byte col
  const __bf16* gA = A + (size_t)(bm * BM + srow) * LDIM + (scb >> 1);
  const __bf16* gB = B + (size_t)(bn * BN + srow) * LDIM + (scb >> 1);

  // ---- fragment read map (swizzled) -------------------------------------
  const int fr = lane & 15;          // row-in-fragment (both operands)
  const int q = lane >> 4;           // k-quad
  const int rsw = (fr & 7) << 4;     // row XOR term

  f32x4 acc[2][4] = {};

#define STAGE(buf, kt)                                                       \
  {                                                                          \
    _Pragma("unroll") for (int c = 0; c < 2; ++c) {                          \
      gld_lds16(gA + (size_t)(c * 64) * LDIM + (kt)*BK,                      \
                &As[buf][c * 4096 + wid * 512]);                             \
      gld_lds16(gB + (size_t)(c * 64) * LDIM + (kt)*BK,                      \
                &Bs[buf][c * 4096 + wid * 512]);                             \
    }                                                                        \
  }

#define COMPUTE(buf)                                                         \
  {                                                                          \
    _Pragma("unroll") for (int ks = 0; ks < 2; ++ks) {                       \
      bf16x8 af[2], bv[4];                                                   \
      const int kb = (((ks << 6) | (q << 4)) ^ rsw) >> 1;                    \
      _Pragma("unroll") for (int m = 0; m < 2; ++m)                          \
          af[m] = *reinterpret_cast<const bf16x8*>(                          \
              &As[buf][(wr * 32 + m * 16 + fr) * BK + kb]);                  \
      _Pragma("unroll") for (int n = 0; n < 4; ++n)                          \
          bv[n] = *reinterpret_cast<const bf16x8*>(                          \
              &Bs[buf][(wc * 64 + n * 16 + fr) * BK + kb]);                  \
      _Pragma("unroll") for (int m = 0; m < 2; ++m)                          \
          _Pragma("unroll") for (int n = 0; n < 4; ++n)                      \
              acc[m][n] = __builtin_amdgcn_mfma_f32_16x16x32_bf16(           \
                  bv[n], af[m], acc[m][n], 0, 0, 0);                         \
    }                                                                        \
  }

  STAGE(0, 0);
  __syncthreads();
#pragma unroll
  for (int kt = 0; kt < 3; ++kt) {
    STAGE((kt + 1) & 1, kt + 1);   // prefetch BEFORE compute (T3 recipe)
    COMPUTE(kt & 1);
    __syncthreads();               // one vmcnt(0)+barrier per K-tile
  }
  COMPUTE(1);

  // ---- epilogue: swapped mfma(B,A) => lane&15 = C-row, regs = 4
  // consecutive C-cols -> one dwordx4 store per fragment.
  float* Cp = C + (size_t)(bm * BM + wr * 32 + fr) * NDIM +
              (bn * BN + wc * 64 + (q << 2));
#pragma unroll
  for (int m = 0; m < 2; ++m)
#pragma unroll
    for (int n = 0; n < 4; ++n)
      *reinterpret_cast<f32x4*>(Cp + (size_t)(m * 16) * NDIM + n * 16) =
          acc[m][n];
#undef STAGE
#undef COMPUTE
}

extern "C" void kernel_launch(void* const* d_in, const int* in_sizes, int n_in,
                              void* d_out, int out_size, void* d_ws, size_t ws_size,
                              hipStream_t stream) {
  const float* user_w = (const float*)d_in[0];
  const float* item_w = (const float*)d_in[1];
  // d_in[2], d_in[3]: indices (unused on test path); d_in[4]: is_test == 1.
  float* out = (float*)d_out;

  unsigned short* un = (unsigned short*)d_ws;             // 4 MB
  unsigned short* vn = un + (size_t)NROWS * LDIM;         // 4 MB

  normalize_both<<<(2 * NROWS) / 4, 256, 0, stream>>>(user_w, item_w, un);

  dim3 grid((NDIM / BM) * (NDIM / BN));
  cos_gemm<<<grid, 512, 0, stream>>>((const __bf16*)un, (const __bf16*)vn, out);
}

// Round 4
// 92.484 us; speedup vs baseline: 1.0934x; 1.0934x over previous
//
#include <hip/hip_runtime.h>
#include <hip/hip_bf16.h>
#include <stdint.h>

// ---------------------------------------------------------------------------
// MF cosine-similarity, test path:
//   C[u][i] = Un[u].Vn[i]; Un/Vn = fp32-normalized rows rounded to bf16.
//
// R4 structure: NO LDS, NO barriers. The normalize kernel writes Un/Vn in
// FRAGMENT-LINEAR layout: for row r, k:  p=r>>4, fr=r&15, kt=k>>5, q=(k>>3)&3,
// j=k&7; byte = p*8192 + kt*1024 + (q*16+fr)*16 + j*2.  A wave's MFMA operand
// fragment (16 rows x 32 k) is then exactly the contiguous 1KB at
// p*8192 + kt*1024 + lane*16 -> global_load_dwordx4, fully coalesced,
// L2-resident (per-XCD working set ~1.5MB). GEMM: 4 waves x 64x64, 8 K-steps,
// even/odd register double-buffer, swapped mfma(B,A) -> f32x4 C stores.
// ---------------------------------------------------------------------------

#define LDIM 256
#define NROWS 8192
#define NDIM 8192
#define BM 128
#define BN 128

typedef __bf16 bf16x8 __attribute__((ext_vector_type(8)));
typedef float f32x4 __attribute__((ext_vector_type(4)));

__device__ __forceinline__ unsigned short f2bf_rne(float f) {
  union { float f; uint32_t u; } c;
  c.f = f;
  uint32_t u = c.u;
  u += 0x7FFFu + ((u >> 16) & 1u);   // round-to-nearest-even
  return (unsigned short)(u >> 16);
}

// One wave per row; writes fragment-linear bf16. Rows 0..8191 = user table
// (dst base 0), rows 8192..16383 = item table (dst base 2M elems).
__global__ __launch_bounds__(256) void normalize_frag(
    const float* __restrict__ userw, const float* __restrict__ itemw,
    unsigned short* __restrict__ dst) {
  const int wave = threadIdx.x >> 6;
  const int lane = threadIdx.x & 63;
  const int row = blockIdx.x * 4 + wave;               // 0..16383
  const float* src = (row < NROWS)
                         ? userw + (size_t)row * LDIM
                         : itemw + (size_t)(row - NROWS) * LDIM;

  const float4 v = reinterpret_cast<const float4*>(src)[lane];  // k=4l..4l+3
  float ss = v.x * v.x + v.y * v.y + v.z * v.z + v.w * v.w;
#pragma unroll
  for (int off = 32; off; off >>= 1) ss += __shfl_xor(ss, off, 64);
  const float rn = 1.0f / fmaxf(sqrtf(ss), 1e-8f);

  ushort4 o;
  o.x = f2bf_rne(v.x * rn);
  o.y = f2bf_rne(v.y * rn);
  o.z = f2bf_rne(v.z * rn);
  o.w = f2bf_rne(v.w * rn);

  // frag-linear elem offset: p*4096 + kt*512 + q*128 + fr*8 + j
  // k = 4*lane: kt = lane>>3, q = (lane>>1)&3, j = (lane&1)*4
  const size_t base = (row < NROWS ? 0 : (size_t)NROWS * LDIM) +
                      (size_t)((row & 8191) >> 4) * 4096;
  const size_t off = base + ((lane >> 3) << 9) + (((lane >> 1) & 3) << 7) +
                     ((row & 15) << 3) + ((lane & 1) << 2);
  *reinterpret_cast<ushort4*>(dst + off) = o;
}

// NT GEMM, no LDS: C[8192][8192] f32 from fragment-linear bf16 A (user) and
// B (item). Grid (64,64): x=bn-major => per-XCD L2 working set ~1.5MB.
__global__ __launch_bounds__(256) void cos_gemm(
    const __bf16* __restrict__ A, const __bf16* __restrict__ B,
    float* __restrict__ C) {
  const int tid = threadIdx.x;
  const int wid = tid >> 6;
  const int lane = tid & 63;
  const int bn = blockIdx.x, bm = blockIdx.y;
  const int wr = wid >> 1, wc = wid & 1;   // wave -> 64x64 sub-tile

  // chunk units (bf16x8 = 16B): panel stride 512 chunks, kt stride 64 chunks
  const bf16x8* pa =
      reinterpret_cast<const bf16x8*>(A) + (size_t)(bm * 8 + wr * 4) * 512 + lane;
  const bf16x8* pb =
      reinterpret_cast<const bf16x8*>(B) + (size_t)(bn * 8 + wc * 4) * 512 + lane;

  f32x4 acc[4][4] = {};
  bf16x8 a0[4], b0[4], a1[4], b1[4];

#define LD(aa, bb, kt)                                                       \
  {                                                                          \
    _Pragma("unroll") for (int m = 0; m < 4; ++m) aa[m] =                    \
        pa[m * 512 + (kt)*64];                                               \
    _Pragma("unroll") for (int n = 0; n < 4; ++n) bb[n] =                    \
        pb[n * 512 + (kt)*64];                                               \
  }
#define STEP(aa, bb)                                                         \
  {                                                                          \
    _Pragma("unroll") for (int m = 0; m < 4; ++m)                            \
        _Pragma("unroll") for (int n = 0; n < 4; ++n)                        \
            acc[m][n] = __builtin_amdgcn_mfma_f32_16x16x32_bf16(             \
                bb[n], aa[m], acc[m][n], 0, 0, 0);                           \
  }

  LD(a0, b0, 0);
#pragma unroll
  for (int kt = 0; kt < 8; kt += 2) {
    if (kt + 1 < 8) LD(a1, b1, kt + 1);
    STEP(a0, b0);
    if (kt + 2 < 8) LD(a0, b0, kt + 2);
    STEP(a1, b1);
  }
#undef LD
#undef STEP

  // Epilogue (R2-verified): swapped mfma(B,A) => lane&15 = C-row (user),
  // regs = 4 consecutive C-cols (item) -> one dwordx4 store per fragment.
  const int fr = lane & 15, q = lane >> 4;
  float* Cp = C + (size_t)(bm * BM + wr * 64 + fr) * NDIM +
              (bn * BN + wc * 64 + (q << 2));
#pragma unroll
  for (int m = 0; m < 4; ++m)
#pragma unroll
    for (int n = 0; n < 4; ++n)
      *reinterpret_cast<f32x4*>(Cp + (size_t)(m * 16) * NDIM + n * 16) =
          acc[m][n];
}

extern "C" void kernel_launch(void* const* d_in, const int* in_sizes, int n_in,
                              void* d_out, int out_size, void* d_ws, size_t ws_size,
                              hipStream_t stream) {
  const float* user_w = (const float*)d_in[0];
  const float* item_w = (const float*)d_in[1];
  // d_in[2], d_in[3]: indices (unused on test path); d_in[4]: is_test == 1.
  float* out = (float*)d_out;

  unsigned short* un = (unsigned short*)d_ws;             // 4 MB frag-linear
  unsigned short* vn = un + (size_t)NROWS * LDIM;         // 4 MB frag-linear

  normalize_frag<<<(2 * NROWS) / 4, 256, 0, stream>>>(user_w, item_w, un);

  dim3 grid(NDIM / BN, NDIM / BM);
  cos_gemm<<<grid, 256, 0, stream>>>((const __bf16*)un, (const __bf16*)vn, out);
}

// Round 5
// 76.646 us; speedup vs baseline: 1.3193x; 1.2066x over previous
//
#include <hip/hip_runtime.h>
#include <hip/hip_bf16.h>
#include <stdint.h>

// ---------------------------------------------------------------------------
// MF cosine-similarity, test path:
//   C[u][i] = Un[u].Vn[i]; Un/Vn = fp32-normalized rows rounded to bf16.
//
// R5 = R1 (best so far, 78us) + ONE change: full-line C stores.
//   R1..R4 all shared a scattered-16B/lane C epilogue (64B per 128B line per
//   instruction) and all landed 78-101us vs a ~39us pure-write floor at the
//   measured 6.9 TB/s fill BW. Hypothesis: partial-line write penalty.
//   Fix: swapped-operand MFMA (R2-validated layout) + 4-pass LDS transpose
//   epilogue; each 32-lane half-wave stores one fully-contiguous 512B row
//   (4 x 128B full lines per store instruction). Loop body is R1's exact
//   BK=32 / 4-wave / 2-barrier structure.
// ---------------------------------------------------------------------------

#define LDIM 256
#define NROWS 8192
#define NDIM 8192
#define BM 128
#define BN 128
#define BK 32

typedef __bf16 bf16x8 __attribute__((ext_vector_type(8)));
typedef float f32x4 __attribute__((ext_vector_type(4)));

__device__ __forceinline__ unsigned short f2bf_rne(float f) {
  union { float f; uint32_t u; } c;
  c.f = f;
  uint32_t u = c.u;
  u += 0x7FFFu + ((u >> 16) & 1u);   // round-to-nearest-even
  return (unsigned short)(u >> 16);
}

// One wave per row, both tables in one launch: 256 f32 -> norm -> 256 bf16,
// row-major output (as R1/R2).
__global__ __launch_bounds__(256) void normalize_both(
    const float* __restrict__ userw, const float* __restrict__ itemw,
    unsigned short* __restrict__ dst) {
  const int wave = threadIdx.x >> 6;
  const int lane = threadIdx.x & 63;
  const int row = blockIdx.x * 4 + wave;               // 0..16383
  const float* src = (row < NROWS)
                         ? userw + (size_t)row * LDIM
                         : itemw + (size_t)(row - NROWS) * LDIM;

  const float4 v = reinterpret_cast<const float4*>(src)[lane];
  float ss = v.x * v.x + v.y * v.y + v.z * v.z + v.w * v.w;
#pragma unroll
  for (int off = 32; off; off >>= 1) ss += __shfl_xor(ss, off, 64);
  const float rn = 1.0f / fmaxf(sqrtf(ss), 1e-8f);

  ushort4 o;
  o.x = f2bf_rne(v.x * rn);
  o.y = f2bf_rne(v.y * rn);
  o.z = f2bf_rne(v.z * rn);
  o.w = f2bf_rne(v.w * rn);
  reinterpret_cast<ushort4*>(dst + (size_t)row * LDIM)[lane] = o;
}

__device__ __forceinline__ void gld_lds16(const __bf16* g, __bf16* l) {
  __builtin_amdgcn_global_load_lds(
      (const __attribute__((address_space(1))) uint32_t*)g,
      (__attribute__((address_space(3))) uint32_t*)l, 16, 0, 0);
}

// NT GEMM: C[8192][8192] f32 = A[8192][256] * B[8192][256]^T, bf16 inputs.
__global__ __launch_bounds__(256) void cos_gemm(
    const __bf16* __restrict__ A, const __bf16* __restrict__ B,
    float* __restrict__ C) {
  __shared__ __bf16 As[BM][BK];      // 8 KB
  __shared__ __bf16 Bs[BN][BK];      // 8 KB
  __shared__ float ep[32][132];      // 16.5 KB epilogue transpose buffer

  const int tid  = threadIdx.x;
  const int wid  = tid >> 6;
  const int lane = tid & 63;
  const int bn = blockIdx.x;
  const int bm = blockIdx.y;
  const int wr = wid >> 1;        // wave row (0..1) -> 64-row slab
  const int wc = wid & 1;         // wave col (0..1) -> 64-col slab

  // Staging map (R1-exact): LDS dest is wave-uniform base + lane*16.
  const int m0 = (wid << 5) + (lane >> 2);   // + c*16 per call
  const int k0 = (lane & 3) << 3;

  const __bf16* gA = A + (size_t)(bm * BM + m0) * LDIM + k0;
  const __bf16* gB = B + (size_t)(bn * BN + m0) * LDIM + k0;
  __bf16* lA = &As[0][0] + (wid << 10);
  __bf16* lB = &Bs[0][0] + (wid << 10);

  const int fr = lane & 15;         // row-in-fragment (both operands)
  const int q = lane >> 4;          // 0..3
  const int kq = q << 3;            // k-offset of this lane's 8 elems

  f32x4 acc[4][4] = {};

  for (int kt = 0; kt < LDIM / BK; ++kt) {
    const int ko = kt * BK;
#pragma unroll
    for (int c = 0; c < 2; ++c) {
      gld_lds16(gA + (size_t)(c * 16) * LDIM + ko, lA + (c << 9));
      gld_lds16(gB + (size_t)(c * 16) * LDIM + ko, lB + (c << 9));
    }
    __syncthreads();

    bf16x8 af[4], bv[4];
#pragma unroll
    for (int m = 0; m < 4; ++m)
      af[m] = *reinterpret_cast<const bf16x8*>(&As[wr * 64 + m * 16 + fr][kq]);
#pragma unroll
    for (int n = 0; n < 4; ++n)
      bv[n] = *reinterpret_cast<const bf16x8*>(&Bs[wc * 64 + n * 16 + fr][kq]);

    // Swapped operands (R2-validated): lane fr = C-row (user), regs = 4
    // consecutive C-cols (item) at q*4.
#pragma unroll
    for (int m = 0; m < 4; ++m)
#pragma unroll
      for (int n = 0; n < 4; ++n)
        acc[m][n] = __builtin_amdgcn_mfma_f32_16x16x32_bf16(bv[n], af[m],
                                                            acc[m][n], 0, 0, 0);
    __syncthreads();
  }

  // ---- full-line store epilogue ------------------------------------------
  // Pass p stages 32 C-rows (wr in {0,1} x 16 rows of fragment-row p) x 128
  // cols into LDS, then 32-lane groups store fully-contiguous 512B rows.
  float* Cbase = C + (size_t)(bm * BM) * NDIM + bn * BN;
#pragma unroll
  for (int p = 0; p < 4; ++p) {
#pragma unroll
    for (int n = 0; n < 4; ++n)
      *reinterpret_cast<f32x4*>(&ep[wr * 16 + fr][wc * 64 + n * 16 + (q << 2)]) =
          acc[p][n];
    __syncthreads();
#pragma unroll
    for (int s = 0; s < 4; ++s) {
      const int r = s * 8 + (tid >> 5);                       // LDS row 0..31
      const int grow = ((r >> 4) << 6) + (p << 4) + (r & 15); // tile row
      *reinterpret_cast<f32x4*>(Cbase + (size_t)grow * NDIM + ((tid & 31) << 2)) =
          *reinterpret_cast<const f32x4*>(&ep[r][(tid & 31) << 2]);
    }
    __syncthreads();   // protect ep before next pass overwrites
  }
}

extern "C" void kernel_launch(void* const* d_in, const int* in_sizes, int n_in,
                              void* d_out, int out_size, void* d_ws, size_t ws_size,
                              hipStream_t stream) {
  const float* user_w = (const float*)d_in[0];
  const float* item_w = (const float*)d_in[1];
  // d_in[2], d_in[3]: indices (unused on test path); d_in[4]: is_test == 1.
  float* out = (float*)d_out;

  unsigned short* un = (unsigned short*)d_ws;             // 4 MB
  unsigned short* vn = un + (size_t)NROWS * LDIM;         // 4 MB

  normalize_both<<<(2 * NROWS) / 4, 256, 0, stream>>>(user_w, item_w, un);

  dim3 grid(NDIM / BN, NDIM / BM);
  cos_gemm<<<grid, 256, 0, stream>>>((const __bf16*)un, (const __bf16*)vn, out);
}